// Round 1
// baseline (1756.266 us; speedup 1.0000x reference)
//
#include <hip/hip_runtime.h>
#include <hip/hip_bf16.h>
#include <math.h>

// MoE: T=8192 tokens, D=1024, MLP=4096, E=8, top-2.
// Plan: router -> per-expert token lists; per expert (sequential on stream):
//   W1 transpose+cvt -> GEMM1(+GELU)->H(bf16) -> W2 transpose+cvt -> GEMM2(gate*y += out)
// bf16 MFMA 16x16x32, 128x128 tiles, fp32 accum. ws usage ~97MB.

#define T_TOKENS 8192
#define DIM 1024
#define MLP 4096
#define NEXP 8

#define TM 128
#define TN 128
#define BK 32
#define PAD 40   // 32 + 8 pad: 80B row stride -> b64 LDS ops ~conflict-free

using bf16 = __hip_bfloat16;
typedef __attribute__((ext_vector_type(4))) short short4v;
typedef __attribute__((ext_vector_type(8))) short short8v;
typedef __attribute__((ext_vector_type(4))) float float4v;

// ---------------- x fp32 -> bf16 ----------------
__global__ __launch_bounds__(256) void convert_x(const float* __restrict__ x,
                                                 bf16* __restrict__ xb) {
  size_t i = ((size_t)blockIdx.x * 256 + threadIdx.x) * 4;
  float4 v = *(const float4*)(x + i);
  union { bf16 h[4]; uint2 u; } o;
  o.h[0] = __float2bfloat16(v.x);
  o.h[1] = __float2bfloat16(v.y);
  o.h[2] = __float2bfloat16(v.z);
  o.h[3] = __float2bfloat16(v.w);
  *(uint2*)(xb + i) = o.u;
}

// ---------------- W [K][N] fp32 -> Wt [N][K] bf16 ----------------
__global__ void transpose_cvt(const float* __restrict__ W, bf16* __restrict__ Wt,
                              int K, int N) {
  __shared__ float tile[32][33];
  int bn = blockIdx.x * 32;
  int bk = blockIdx.y * 32;
  int tx = threadIdx.x, ty = threadIdx.y;  // 32 x 8
#pragma unroll
  for (int j = 0; j < 4; j++)
    tile[ty + j * 8][tx] = W[(size_t)(bk + ty + j * 8) * N + bn + tx];
  __syncthreads();
#pragma unroll
  for (int j = 0; j < 4; j++)
    Wt[(size_t)(bn + ty + j * 8) * K + bk + tx] =
        __float2bfloat16(tile[tx][ty + j * 8]);
}

// ---------------- router: one wave per token ----------------
__global__ __launch_bounds__(256) void router_kernel(
    const float* __restrict__ x, const float* __restrict__ rw,
    const float* __restrict__ rb, const float* __restrict__ eb,
    int* __restrict__ counts, int* __restrict__ toks, float* __restrict__ gates) {
  __shared__ float rws[NEXP][DIM];  // transposed router_w, 32KB
  for (int i = threadIdx.x; i < NEXP * DIM; i += 256) {
    int d = i >> 3, e = i & 7;
    rws[e][d] = rw[i];
  }
  __syncthreads();
  int wave = threadIdx.x >> 6, lane = threadIdx.x & 63;
  int t = blockIdx.x * 4 + wave;
  const float* xr = x + (size_t)t * DIM;
  float acc[NEXP];
#pragma unroll
  for (int e = 0; e < NEXP; e++) acc[e] = 0.f;
  for (int d = lane; d < DIM; d += 64) {
    float xv = xr[d];
#pragma unroll
    for (int e = 0; e < NEXP; e++) acc[e] += xv * rws[e][d];
  }
#pragma unroll
  for (int e = 0; e < NEXP; e++) {
#pragma unroll
    for (int off = 32; off > 0; off >>= 1) acc[e] += __shfl_xor(acc[e], off, 64);
  }
  if (lane == 0) {
    float l[NEXP], m = -1e30f;
#pragma unroll
    for (int e = 0; e < NEXP; e++) {
      l[e] = acc[e] + rb[e] + eb[e];
      m = fmaxf(m, l[e]);
    }
    float p[NEXP], s = 0.f;
#pragma unroll
    for (int e = 0; e < NEXP; e++) { p[e] = expf(l[e] - m); s += p[e]; }
    float inv = 1.f / s;
#pragma unroll
    for (int e = 0; e < NEXP; e++) p[e] *= inv;
    int i0 = 0;
#pragma unroll
    for (int e = 1; e < NEXP; e++) if (p[e] > p[i0]) i0 = e;
    int i1 = (i0 == 0) ? 1 : 0;
#pragma unroll
    for (int e = 0; e < NEXP; e++) if (e != i0 && p[e] > p[i1]) i1 = e;
    float v0 = p[i0], v1 = p[i1];
    float sn = v0 + v1 + 1e-9f;
    float g0 = v0 / sn, g1 = v1 / sn;
    int q0 = atomicAdd(&counts[i0], 1);
    toks[i0 * T_TOKENS + q0] = t;
    gates[i0 * T_TOKENS + q0] = g0;
    int q1 = atomicAdd(&counts[i1], 1);
    toks[i1 * T_TOKENS + q1] = t;
    gates[i1 * T_TOKENS + q1] = g1;
  }
}

// ---------------- GEMM1: H[pos] = gelu(X[tok[pos]] @ W1 + b1) ----------------
__global__ __launch_bounds__(256) void moe_gemm1(
    const bf16* __restrict__ Xb, const bf16* __restrict__ Wt,
    const float* __restrict__ bias, bf16* __restrict__ H,
    const int* __restrict__ toks, const int* __restrict__ cntp) {
  const int K = DIM;
  int ne = *cntp;
  int row0 = blockIdx.y * TM;
  if (row0 >= ne) return;
  int col0 = blockIdx.x * TN;

  __shared__ __align__(16) bf16 As[TM][PAD];
  __shared__ __align__(16) bf16 Bs[TN][PAD];
  __shared__ int tids[TM];

  int tid = threadIdx.x;
  if (tid < TM) {
    int r = row0 + tid;
    tids[tid] = toks[r < ne ? r : ne - 1];
  }
  __syncthreads();

  int wave = tid >> 6, lane = tid & 63;
  int wr = (wave >> 1) * 64, wc = (wave & 1) * 64;
  int lr = lane & 15, quad = lane >> 4;

  int srow = tid >> 1;
  int sseg = (tid & 1) * 16;
  const bf16* arow = Xb + (size_t)tids[srow] * K + sseg;
  const bf16* brow = Wt + (size_t)(col0 + srow) * K + sseg;

  float4v acc[4][4];
#pragma unroll
  for (int i = 0; i < 4; i++)
#pragma unroll
    for (int j = 0; j < 4; j++) acc[i][j] = (float4v)0.0f;

  for (int k0 = 0; k0 < K; k0 += BK) {
    uint4 av0 = *(const uint4*)(arow + k0);
    uint4 av1 = *(const uint4*)(arow + k0 + 8);
    uint4 bv0 = *(const uint4*)(brow + k0);
    uint4 bv1 = *(const uint4*)(brow + k0 + 8);
    uint2* ad = (uint2*)&As[srow][sseg];
    ad[0] = make_uint2(av0.x, av0.y);
    ad[1] = make_uint2(av0.z, av0.w);
    ad[2] = make_uint2(av1.x, av1.y);
    ad[3] = make_uint2(av1.z, av1.w);
    uint2* bd = (uint2*)&Bs[srow][sseg];
    bd[0] = make_uint2(bv0.x, bv0.y);
    bd[1] = make_uint2(bv0.z, bv0.w);
    bd[2] = make_uint2(bv1.x, bv1.y);
    bd[3] = make_uint2(bv1.z, bv1.w);
    __syncthreads();

    short8v a[4], b[4];
#pragma unroll
    for (int mt = 0; mt < 4; mt++) {
      const short* p = (const short*)&As[wr + mt * 16 + lr][quad * 8];
      short4v lo = *(const short4v*)p;
      short4v hi = *(const short4v*)(p + 4);
      a[mt] = __builtin_shufflevector(lo, hi, 0, 1, 2, 3, 4, 5, 6, 7);
    }
#pragma unroll
    for (int nt = 0; nt < 4; nt++) {
      const short* p = (const short*)&Bs[wc + nt * 16 + lr][quad * 8];
      short4v lo = *(const short4v*)p;
      short4v hi = *(const short4v*)(p + 4);
      b[nt] = __builtin_shufflevector(lo, hi, 0, 1, 2, 3, 4, 5, 6, 7);
    }
#pragma unroll
    for (int mt = 0; mt < 4; mt++)
#pragma unroll
      for (int nt = 0; nt < 4; nt++)
        acc[mt][nt] = __builtin_amdgcn_mfma_f32_16x16x32_bf16(a[mt], b[nt],
                                                              acc[mt][nt], 0, 0, 0);
    __syncthreads();
  }

#pragma unroll
  for (int mt = 0; mt < 4; mt++) {
#pragma unroll
    for (int r = 0; r < 4; r++) {
      int gr = wr + mt * 16 + quad * 4 + r;
      if (row0 + gr < ne) {
#pragma unroll
        for (int nt = 0; nt < 4; nt++) {
          int gc = col0 + wc + nt * 16 + lr;
          float v = acc[mt][nt][r] + bias[gc];
          v = 0.5f * v * (1.0f + erff(v * 0.70710678118f));  // exact-erf GELU
          H[(size_t)(row0 + gr) * MLP + gc] = __float2bfloat16(v);
        }
      }
    }
  }
}

// ---------------- GEMM2: out[tok[pos]] += gate[pos] * (H[pos] @ W2 + b2) ----------------
__global__ __launch_bounds__(256) void moe_gemm2(
    const bf16* __restrict__ H, const bf16* __restrict__ Wt,
    const float* __restrict__ bias, float* __restrict__ out,
    const int* __restrict__ toks, const float* __restrict__ gates,
    const int* __restrict__ cntp) {
  const int K = MLP;
  int ne = *cntp;
  int row0 = blockIdx.y * TM;
  if (row0 >= ne) return;
  int col0 = blockIdx.x * TN;

  __shared__ __align__(16) bf16 As[TM][PAD];
  __shared__ __align__(16) bf16 Bs[TN][PAD];

  int tid = threadIdx.x;
  int wave = tid >> 6, lane = tid & 63;
  int wr = (wave >> 1) * 64, wc = (wave & 1) * 64;
  int lr = lane & 15, quad = lane >> 4;

  int srow = tid >> 1;
  int sseg = (tid & 1) * 16;
  int arow_i = row0 + srow;  // always < 8192, in-bounds of H
  const bf16* arow = H + (size_t)arow_i * K + sseg;
  const bf16* brow = Wt + (size_t)(col0 + srow) * K + sseg;

  float4v acc[4][4];
#pragma unroll
  for (int i = 0; i < 4; i++)
#pragma unroll
    for (int j = 0; j < 4; j++) acc[i][j] = (float4v)0.0f;

  for (int k0 = 0; k0 < K; k0 += BK) {
    uint4 av0 = *(const uint4*)(arow + k0);
    uint4 av1 = *(const uint4*)(arow + k0 + 8);
    uint4 bv0 = *(const uint4*)(brow + k0);
    uint4 bv1 = *(const uint4*)(brow + k0 + 8);
    uint2* ad = (uint2*)&As[srow][sseg];
    ad[0] = make_uint2(av0.x, av0.y);
    ad[1] = make_uint2(av0.z, av0.w);
    ad[2] = make_uint2(av1.x, av1.y);
    ad[3] = make_uint2(av1.z, av1.w);
    uint2* bd = (uint2*)&Bs[srow][sseg];
    bd[0] = make_uint2(bv0.x, bv0.y);
    bd[1] = make_uint2(bv0.z, bv0.w);
    bd[2] = make_uint2(bv1.x, bv1.y);
    bd[3] = make_uint2(bv1.z, bv1.w);
    __syncthreads();

    short8v a[4], b[4];
#pragma unroll
    for (int mt = 0; mt < 4; mt++) {
      const short* p = (const short*)&As[wr + mt * 16 + lr][quad * 8];
      short4v lo = *(const short4v*)p;
      short4v hi = *(const short4v*)(p + 4);
      a[mt] = __builtin_shufflevector(lo, hi, 0, 1, 2, 3, 4, 5, 6, 7);
    }
#pragma unroll
    for (int nt = 0; nt < 4; nt++) {
      const short* p = (const short*)&Bs[wc + nt * 16 + lr][quad * 8];
      short4v lo = *(const short4v*)p;
      short4v hi = *(const short4v*)(p + 4);
      b[nt] = __builtin_shufflevector(lo, hi, 0, 1, 2, 3, 4, 5, 6, 7);
    }
#pragma unroll
    for (int mt = 0; mt < 4; mt++)
#pragma unroll
      for (int nt = 0; nt < 4; nt++)
        acc[mt][nt] = __builtin_amdgcn_mfma_f32_16x16x32_bf16(a[mt], b[nt],
                                                              acc[mt][nt], 0, 0, 0);
    __syncthreads();
  }

#pragma unroll
  for (int mt = 0; mt < 4; mt++) {
#pragma unroll
    for (int r = 0; r < 4; r++) {
      int gr = wr + mt * 16 + quad * 4 + r;
      int grow = row0 + gr;
      if (grow < ne) {
        int t = toks[grow];
        float g = gates[grow];
#pragma unroll
        for (int nt = 0; nt < 4; nt++) {
          int gc = col0 + wc + nt * 16 + lr;
          float v = g * (acc[mt][nt][r] + bias[gc]);
          // experts run sequentially and each (t,gc) is owned by one block
          // within a launch -> plain RMW is race-free.
          out[(size_t)t * DIM + gc] += v;
        }
      }
    }
  }
}

extern "C" void kernel_launch(void* const* d_in, const int* in_sizes, int n_in,
                              void* d_out, int out_size, void* d_ws, size_t ws_size,
                              hipStream_t stream) {
  const float* x  = (const float*)d_in[0];
  const float* rw = (const float*)d_in[1];
  const float* rb = (const float*)d_in[2];
  const float* eb = (const float*)d_in[3];
  const float* w1 = (const float*)d_in[4];
  const float* b1 = (const float*)d_in[5];
  const float* w2 = (const float*)d_in[6];
  const float* b2 = (const float*)d_in[7];
  float* out = (float*)d_out;

  char* ws = (char*)d_ws;
  bf16* xb    = (bf16*)ws;                             // 16 MB
  bf16* w1t   = (bf16*)(ws + (size_t)(16 << 20));      // 8 MB  [MLP][DIM]
  bf16* w2t   = (bf16*)(ws + (size_t)(24 << 20));      // 8 MB  [DIM][MLP]
  bf16* Hbuf  = (bf16*)(ws + (size_t)(32 << 20));      // 64 MB [T][MLP]
  int*  counts = (int*)(ws + (size_t)(96 << 20));
  int*  toks   = (int*)(ws + (size_t)(96 << 20) + 1024);
  float* gates = (float*)(ws + (size_t)(96 << 20) + 1024 +
                          (size_t)NEXP * T_TOKENS * sizeof(int));

  hipMemsetAsync(counts, 0, NEXP * sizeof(int), stream);
  hipMemsetAsync(d_out, 0, (size_t)T_TOKENS * DIM * sizeof(float), stream);

  convert_x<<<(T_TOKENS * DIM) / (256 * 4), 256, 0, stream>>>(x, xb);
  router_kernel<<<T_TOKENS / 4, 256, 0, stream>>>(x, rw, rb, eb, counts, toks, gates);

  for (int e = 0; e < NEXP; e++) {
    transpose_cvt<<<dim3(MLP / 32, DIM / 32), dim3(32, 8), 0, stream>>>(
        w1 + (size_t)e * DIM * MLP, w1t, DIM, MLP);
    moe_gemm1<<<dim3(MLP / TN, T_TOKENS / TM), 256, 0, stream>>>(
        xb, w1t, b1 + (size_t)e * MLP, Hbuf, toks + e * T_TOKENS, counts + e);
    transpose_cvt<<<dim3(DIM / 32, MLP / 32), dim3(32, 8), 0, stream>>>(
        w2 + (size_t)e * MLP * DIM, w2t, MLP, DIM);
    moe_gemm2<<<dim3(DIM / TN, T_TOKENS / TM), 256, 0, stream>>>(
        Hbuf, w2t, b2 + (size_t)e * DIM, out, toks + e * T_TOKENS,
        gates + e * T_TOKENS, counts + e);
  }
}

// Round 2
// 1232.352 us; speedup vs baseline: 1.4251x; 1.4251x over previous
//
#include <hip/hip_runtime.h>
#include <hip/hip_bf16.h>
#include <math.h>

// MoE: T=8192 tokens, D=1024, MLP=4096, E=8, top-2.
// Round 2: (a) router split into compute(no atomics)+build_lists(LDS hist),
// (b) GEMMs use m97 recipe: global_load_lds width=16, unpadded LDS, b128 frags,
// (c) 64x64 transpose tiles. Experts sequential on stream (ws ~97MB).

#define T_TOKENS 8192
#define DIM 1024
#define MLP 4096
#define NEXP 8

using bf16 = __hip_bfloat16;
typedef __attribute__((ext_vector_type(8))) short short8v;
typedef __attribute__((ext_vector_type(4))) float float4v;

__device__ __forceinline__ void gl2lds16(const void* g, void* l) {
  __builtin_amdgcn_global_load_lds(
      (const __attribute__((address_space(1))) unsigned int*)g,
      (__attribute__((address_space(3))) unsigned int*)l, 16, 0, 0);
}

// ---------------- router + x->bf16 convert (fused) ----------------
// 512 blocks x 256 thr; block stages rw once, handles 16 tokens (wave: 4).
__global__ __launch_bounds__(256) void router_convert(
    const float* __restrict__ x, const float* __restrict__ rw,
    const float* __restrict__ rb, const float* __restrict__ eb,
    bf16* __restrict__ xb, int4* __restrict__ tokinfo) {
  __shared__ float rws[NEXP][DIM];  // [e][d], 32 KB
  __shared__ float rbe[NEXP];
  for (int i = threadIdx.x; i < NEXP * DIM; i += 256)
    rws[i & 7][i >> 3] = rw[i];
  if (threadIdx.x < NEXP) rbe[threadIdx.x] = rb[threadIdx.x] + eb[threadIdx.x];
  __syncthreads();
  int wave = threadIdx.x >> 6, lane = threadIdx.x & 63;
  for (int i = 0; i < 4; i++) {
    int t = blockIdx.x * 16 + wave * 4 + i;
    const float4* xr = (const float4*)(x + (size_t)t * DIM);
    float acc[NEXP];
#pragma unroll
    for (int e = 0; e < NEXP; e++) acc[e] = 0.f;
#pragma unroll
    for (int it = 0; it < 4; it++) {
      float4 xv = xr[it * 64 + lane];
      union { bf16 h[4]; uint2 u; } o;
      o.h[0] = __float2bfloat16(xv.x);
      o.h[1] = __float2bfloat16(xv.y);
      o.h[2] = __float2bfloat16(xv.z);
      o.h[3] = __float2bfloat16(xv.w);
      *(uint2*)(xb + (size_t)t * DIM + (it * 64 + lane) * 4) = o.u;
#pragma unroll
      for (int e = 0; e < NEXP; e++) {
        float4 rv = ((const float4*)rws[e])[it * 64 + lane];  // contiguous b128
        acc[e] += xv.x * rv.x + xv.y * rv.y + xv.z * rv.z + xv.w * rv.w;
      }
    }
#pragma unroll
    for (int e = 0; e < NEXP; e++) {
#pragma unroll
      for (int off = 32; off > 0; off >>= 1) acc[e] += __shfl_xor(acc[e], off, 64);
    }
    if (lane == 0) {
      float l[NEXP], m = -1e30f;
#pragma unroll
      for (int e = 0; e < NEXP; e++) { l[e] = acc[e] + rbe[e]; m = fmaxf(m, l[e]); }
      float p[NEXP], s = 0.f;
#pragma unroll
      for (int e = 0; e < NEXP; e++) { p[e] = expf(l[e] - m); s += p[e]; }
      float inv = 1.f / s;
#pragma unroll
      for (int e = 0; e < NEXP; e++) p[e] *= inv;
      int i0 = 0;
#pragma unroll
      for (int e = 1; e < NEXP; e++) if (p[e] > p[i0]) i0 = e;
      int i1 = (i0 == 0) ? 1 : 0;
#pragma unroll
      for (int e = 0; e < NEXP; e++) if (e != i0 && p[e] > p[i1]) i1 = e;
      float sn = p[i0] + p[i1] + 1e-9f;
      tokinfo[t] = make_int4(i0, i1, __float_as_int(p[i0] / sn),
                             __float_as_int(p[i1] / sn));
    }
  }
}

// ---------------- build per-expert lists (LDS-aggregated atomics) ----------
__global__ __launch_bounds__(256) void build_lists(
    const int4* __restrict__ tokinfo, int* __restrict__ counts,
    int* __restrict__ toks, float* __restrict__ gates) {
  __shared__ int hist[NEXP], base[NEXP];
  if (threadIdx.x < NEXP) hist[threadIdx.x] = 0;
  __syncthreads();
  int t = blockIdx.x * 256 + threadIdx.x;
  int4 info = tokinfo[t];
  int r0 = atomicAdd(&hist[info.x], 1);
  int r1 = atomicAdd(&hist[info.y], 1);
  __syncthreads();
  if (threadIdx.x < NEXP)
    base[threadIdx.x] = atomicAdd(&counts[threadIdx.x * 16], hist[threadIdx.x]);
  __syncthreads();
  int p0 = base[info.x] + r0, p1 = base[info.y] + r1;
  toks[info.x * T_TOKENS + p0] = t;
  gates[info.x * T_TOKENS + p0] = __int_as_float(info.z);
  toks[info.y * T_TOKENS + p1] = t;
  gates[info.y * T_TOKENS + p1] = __int_as_float(info.w);
}

// ---------------- W [K][N] fp32 -> Wt [N][K] bf16, 64x64 tiles ------------
__global__ __launch_bounds__(256) void transpose_cvt64(
    const float* __restrict__ W, bf16* __restrict__ Wt, int K, int N) {
  __shared__ float tile[64][65];
  int bn = blockIdx.x * 64, bk = blockIdx.y * 64;
  int tx = threadIdx.x & 15, ty = threadIdx.x >> 4;
#pragma unroll
  for (int j = 0; j < 4; j++) {
    int k = bk + ty + j * 16;
    float4 v = *(const float4*)(W + (size_t)k * N + bn + tx * 4);
    tile[ty + j * 16][tx * 4 + 0] = v.x;
    tile[ty + j * 16][tx * 4 + 1] = v.y;
    tile[ty + j * 16][tx * 4 + 2] = v.z;
    tile[ty + j * 16][tx * 4 + 3] = v.w;
  }
  __syncthreads();
#pragma unroll
  for (int j = 0; j < 4; j++) {
    int n = bn + ty + j * 16;
    union { bf16 h[4]; uint2 u; } o;
    o.h[0] = __float2bfloat16(tile[tx * 4 + 0][ty + j * 16]);
    o.h[1] = __float2bfloat16(tile[tx * 4 + 1][ty + j * 16]);
    o.h[2] = __float2bfloat16(tile[tx * 4 + 2][ty + j * 16]);
    o.h[3] = __float2bfloat16(tile[tx * 4 + 3][ty + j * 16]);
    *(uint2*)(Wt + (size_t)n * K + bk + tx * 4) = o.u;
  }
}

// ---------------- GEMM1: H[pos] = gelu(X[tok[pos]] @ W1 + b1) -------------
// 128x128 tile, BK=32, global_load_lds staging, unpadded LDS.
__global__ __launch_bounds__(256) void moe_gemm1(
    const bf16* __restrict__ Xb, const bf16* __restrict__ Wt,
    const float* __restrict__ bias, bf16* __restrict__ H,
    const int* __restrict__ toks, const int* __restrict__ cntp) {
  int ne = *cntp;
  int row0 = blockIdx.y * 128;
  if (row0 >= ne) return;
  int col0 = blockIdx.x * 128;

  __shared__ __align__(16) bf16 As[128][32];  // 8 KB
  __shared__ __align__(16) bf16 Bs[128][32];  // 8 KB
  __shared__ int tids[128];

  int tid = threadIdx.x;
  if (tid < 128) {
    int r = row0 + tid;
    tids[tid] = toks[r < ne ? r : ne - 1];
  }
  __syncthreads();

  int wave = tid >> 6, lane = tid & 63;
  int wr = (wave >> 1) * 64, wc = (wave & 1) * 64;
  int lr = lane & 15, quad = lane >> 4;
  int r0 = tid >> 2, seg = tid & 3;

  const bf16* pA0 = Xb + (size_t)tids[r0] * DIM + seg * 8;
  const bf16* pA1 = Xb + (size_t)tids[64 + r0] * DIM + seg * 8;
  const bf16* pB0 = Wt + (size_t)(col0 + r0) * DIM + seg * 8;
  const bf16* pB1 = Wt + (size_t)(col0 + 64 + r0) * DIM + seg * 8;
  char* lA = (char*)As + wave * 1024;  // wave-uniform dest, HW adds lane*16
  char* lB = (char*)Bs + wave * 1024;

  float4v acc[4][4];
#pragma unroll
  for (int i = 0; i < 4; i++)
#pragma unroll
    for (int j = 0; j < 4; j++) acc[i][j] = (float4v)0.0f;

  for (int k0 = 0; k0 < DIM; k0 += 32) {
    gl2lds16(pA0 + k0, lA);
    gl2lds16(pA1 + k0, lA + 4096);
    gl2lds16(pB0 + k0, lB);
    gl2lds16(pB1 + k0, lB + 4096);
    __syncthreads();
    short8v a[4], b[4];
#pragma unroll
    for (int mt = 0; mt < 4; mt++)
      a[mt] = *(const short8v*)&As[wr + mt * 16 + lr][quad * 8];
#pragma unroll
    for (int nt = 0; nt < 4; nt++)
      b[nt] = *(const short8v*)&Bs[wc + nt * 16 + lr][quad * 8];
#pragma unroll
    for (int mt = 0; mt < 4; mt++)
#pragma unroll
      for (int nt = 0; nt < 4; nt++)
        acc[mt][nt] = __builtin_amdgcn_mfma_f32_16x16x32_bf16(a[mt], b[nt],
                                                              acc[mt][nt], 0, 0, 0);
    __syncthreads();
  }

#pragma unroll
  for (int mt = 0; mt < 4; mt++) {
#pragma unroll
    for (int r = 0; r < 4; r++) {
      int gr = wr + mt * 16 + quad * 4 + r;
      if (row0 + gr < ne) {
#pragma unroll
        for (int nt = 0; nt < 4; nt++) {
          int gc = col0 + wc + nt * 16 + lr;
          float v = acc[mt][nt][r] + bias[gc];
          v = 0.5f * v * (1.0f + erff(v * 0.70710678118f));  // exact-erf GELU
          H[(size_t)(row0 + gr) * MLP + gc] = __float2bfloat16(v);
        }
      }
    }
  }
}

// ---------------- GEMM2: out[tok[pos]] += g * (H[pos] @ W2 + b2) ----------
// 128x64 tile (4 waves x 32 rows), BK=32, K=4096.
__global__ __launch_bounds__(256) void moe_gemm2(
    const bf16* __restrict__ H, const bf16* __restrict__ Wt,
    const float* __restrict__ bias, float* __restrict__ out,
    const int* __restrict__ toks, const float* __restrict__ gates,
    const int* __restrict__ cntp) {
  int ne = *cntp;
  int row0 = blockIdx.y * 128;
  if (row0 >= ne) return;
  int col0 = blockIdx.x * 64;

  __shared__ __align__(16) bf16 As[128][32];  // 8 KB
  __shared__ __align__(16) bf16 Bs[64][32];   // 4 KB

  int tid = threadIdx.x;
  int wave = tid >> 6, lane = tid & 63;
  int wr = wave * 32;
  int lr = lane & 15, quad = lane >> 4;
  int r0 = tid >> 2, seg = tid & 3;

  const bf16* pA0 = H + (size_t)(row0 + r0) * MLP + seg * 8;
  const bf16* pA1 = H + (size_t)(row0 + 64 + r0) * MLP + seg * 8;
  const bf16* pB0 = Wt + (size_t)(col0 + r0) * MLP + seg * 8;  // r0<64 rows
  char* lA = (char*)As + wave * 1024;
  char* lB = (char*)Bs + wave * 1024;

  float4v acc[2][4];
#pragma unroll
  for (int i = 0; i < 2; i++)
#pragma unroll
    for (int j = 0; j < 4; j++) acc[i][j] = (float4v)0.0f;

  for (int k0 = 0; k0 < MLP; k0 += 32) {
    gl2lds16(pA0 + k0, lA);
    gl2lds16(pA1 + k0, lA + 4096);
    gl2lds16(pB0 + k0, lB);
    __syncthreads();
    short8v a[2], b[4];
#pragma unroll
    for (int mt = 0; mt < 2; mt++)
      a[mt] = *(const short8v*)&As[wr + mt * 16 + lr][quad * 8];
#pragma unroll
    for (int nt = 0; nt < 4; nt++)
      b[nt] = *(const short8v*)&Bs[nt * 16 + lr][quad * 8];
#pragma unroll
    for (int mt = 0; mt < 2; mt++)
#pragma unroll
      for (int nt = 0; nt < 4; nt++)
        acc[mt][nt] = __builtin_amdgcn_mfma_f32_16x16x32_bf16(a[mt], b[nt],
                                                              acc[mt][nt], 0, 0, 0);
    __syncthreads();
  }

#pragma unroll
  for (int mt = 0; mt < 2; mt++) {
#pragma unroll
    for (int r = 0; r < 4; r++) {
      int gr = wr + mt * 16 + quad * 4 + r;
      int grow = row0 + gr;
      if (grow < ne) {
        int t = toks[grow];
        float g = gates[grow];
#pragma unroll
        for (int nt = 0; nt < 4; nt++) {
          int gc = col0 + nt * 16 + lr;
          // experts sequential; unique (t,gc) per block within a launch.
          out[(size_t)t * DIM + gc] += g * (acc[mt][nt][r] + bias[gc]);
        }
      }
    }
  }
}

extern "C" void kernel_launch(void* const* d_in, const int* in_sizes, int n_in,
                              void* d_out, int out_size, void* d_ws, size_t ws_size,
                              hipStream_t stream) {
  const float* x  = (const float*)d_in[0];
  const float* rw = (const float*)d_in[1];
  const float* rb = (const float*)d_in[2];
  const float* eb = (const float*)d_in[3];
  const float* w1 = (const float*)d_in[4];
  const float* b1 = (const float*)d_in[5];
  const float* w2 = (const float*)d_in[6];
  const float* b2 = (const float*)d_in[7];
  float* out = (float*)d_out;

  char* ws = (char*)d_ws;
  bf16* xb   = (bf16*)ws;                          // 16 MB
  bf16* w1t  = (bf16*)(ws + (size_t)(16 << 20));   // 8 MB  [MLP][DIM]
  bf16* w2t  = (bf16*)(ws + (size_t)(24 << 20));   // 8 MB  [DIM][MLP]
  bf16* Hbuf = (bf16*)(ws + (size_t)(32 << 20));   // 64 MB [T][MLP]
  char* aux  = ws + (size_t)(96 << 20);
  int4*  tokinfo = (int4*)aux;                                   // 128 KB
  int*   counts  = (int*)(aux + 131072);                         // 8 x 64B
  int*   toks    = (int*)(aux + 131072 + 512);                   // 256 KB
  float* gates   = (float*)(aux + 131072 + 512 + 262144);        // 256 KB

  hipMemsetAsync(counts, 0, NEXP * 16 * sizeof(int), stream);
  hipMemsetAsync(d_out, 0, (size_t)T_TOKENS * DIM * sizeof(float), stream);

  router_convert<<<T_TOKENS / 16, 256, 0, stream>>>(x, rw, rb, eb, xb, tokinfo);
  build_lists<<<T_TOKENS / 256, 256, 0, stream>>>(tokinfo, counts, toks, gates);

  for (int e = 0; e < NEXP; e++) {
    transpose_cvt64<<<dim3(MLP / 64, DIM / 64), 256, 0, stream>>>(
        w1 + (size_t)e * DIM * MLP, w1t, DIM, MLP);
    moe_gemm1<<<dim3(MLP / 128, T_TOKENS / 128), 256, 0, stream>>>(
        xb, w1t, b1 + (size_t)e * MLP, Hbuf, toks + e * T_TOKENS, counts + e * 16);
    transpose_cvt64<<<dim3(DIM / 64, MLP / 64), 256, 0, stream>>>(
        w2 + (size_t)e * MLP * DIM, w2t, MLP, DIM);
    moe_gemm2<<<dim3(DIM / 64, T_TOKENS / 128), 256, 0, stream>>>(
        Hbuf, w2t, b2 + (size_t)e * DIM, out, toks + e * T_TOKENS,
        gates + e * T_TOKENS, counts + e * 16);
  }
}

// Round 3
// 886.853 us; speedup vs baseline: 1.9803x; 1.3896x over previous
//
#include <hip/hip_runtime.h>
#include <hip/hip_bf16.h>
#include <math.h>

// MoE: T=8192 tokens, D=1024, MLP=4096, E=8, top-2.
// Round 3: fuse all experts into ONE gemm1 + ONE gemm2 launch (128-aligned
// slot space, per-block expert lookup via prefix table, fp32 atomicAdd out).
// Needs ~227MB ws -> guarded by ws_size; fallback = round-2 sequential path.

#define T_TOKENS 8192
#define DIM 1024
#define MLP 4096
#define NEXP 8
#define MAXSLOT 17408   // 136 row-blocks * 128
#define MAXYB 136

using bf16 = __hip_bfloat16;
typedef __attribute__((ext_vector_type(8))) short short8v;
typedef __attribute__((ext_vector_type(4))) float float4v;

__device__ __forceinline__ void gl2lds16(const void* g, void* l) {
  __builtin_amdgcn_global_load_lds(
      (const __attribute__((address_space(1))) unsigned int*)g,
      (__attribute__((address_space(3))) unsigned int*)l, 16, 0, 0);
}

// ---------------- router + x->bf16 convert (fused) ----------------
__global__ __launch_bounds__(256) void router_convert(
    const float* __restrict__ x, const float* __restrict__ rw,
    const float* __restrict__ rb, const float* __restrict__ eb,
    bf16* __restrict__ xb, int4* __restrict__ tokinfo) {
  __shared__ float rws[NEXP][DIM];
  __shared__ float rbe[NEXP];
  for (int i = threadIdx.x; i < NEXP * DIM; i += 256)
    rws[i & 7][i >> 3] = rw[i];
  if (threadIdx.x < NEXP) rbe[threadIdx.x] = rb[threadIdx.x] + eb[threadIdx.x];
  __syncthreads();
  int wave = threadIdx.x >> 6, lane = threadIdx.x & 63;
  for (int i = 0; i < 4; i++) {
    int t = blockIdx.x * 16 + wave * 4 + i;
    const float4* xr = (const float4*)(x + (size_t)t * DIM);
    float acc[NEXP];
#pragma unroll
    for (int e = 0; e < NEXP; e++) acc[e] = 0.f;
#pragma unroll
    for (int it = 0; it < 4; it++) {
      float4 xv = xr[it * 64 + lane];
      union { bf16 h[4]; uint2 u; } o;
      o.h[0] = __float2bfloat16(xv.x);
      o.h[1] = __float2bfloat16(xv.y);
      o.h[2] = __float2bfloat16(xv.z);
      o.h[3] = __float2bfloat16(xv.w);
      *(uint2*)(xb + (size_t)t * DIM + (it * 64 + lane) * 4) = o.u;
#pragma unroll
      for (int e = 0; e < NEXP; e++) {
        float4 rv = ((const float4*)rws[e])[it * 64 + lane];
        acc[e] += xv.x * rv.x + xv.y * rv.y + xv.z * rv.z + xv.w * rv.w;
      }
    }
#pragma unroll
    for (int e = 0; e < NEXP; e++) {
#pragma unroll
      for (int off = 32; off > 0; off >>= 1) acc[e] += __shfl_xor(acc[e], off, 64);
    }
    if (lane == 0) {
      float l[NEXP], m = -1e30f;
#pragma unroll
      for (int e = 0; e < NEXP; e++) { l[e] = acc[e] + rbe[e]; m = fmaxf(m, l[e]); }
      float p[NEXP], s = 0.f;
#pragma unroll
      for (int e = 0; e < NEXP; e++) { p[e] = expf(l[e] - m); s += p[e]; }
      float inv = 1.f / s;
#pragma unroll
      for (int e = 0; e < NEXP; e++) p[e] *= inv;
      int i0 = 0;
#pragma unroll
      for (int e = 1; e < NEXP; e++) if (p[e] > p[i0]) i0 = e;
      int i1 = (i0 == 0) ? 1 : 0;
#pragma unroll
      for (int e = 0; e < NEXP; e++) if (e != i0 && p[e] > p[i1]) i1 = e;
      float sn = p[i0] + p[i1] + 1e-9f;
      tokinfo[t] = make_int4(i0, i1, __float_as_int(p[i0] / sn),
                             __float_as_int(p[i1] / sn));
    }
  }
}

// ---------------- build per-expert lists ----------------
__global__ __launch_bounds__(256) void build_lists(
    const int4* __restrict__ tokinfo, int* __restrict__ counts,
    int* __restrict__ toks, float* __restrict__ gates) {
  __shared__ int hist[NEXP], base[NEXP];
  if (threadIdx.x < NEXP) hist[threadIdx.x] = 0;
  __syncthreads();
  int t = blockIdx.x * 256 + threadIdx.x;
  int4 info = tokinfo[t];
  int r0 = atomicAdd(&hist[info.x], 1);
  int r1 = atomicAdd(&hist[info.y], 1);
  __syncthreads();
  if (threadIdx.x < NEXP)
    base[threadIdx.x] = atomicAdd(&counts[threadIdx.x * 16], hist[threadIdx.x]);
  __syncthreads();
  int p0 = base[info.x] + r0, p1 = base[info.y] + r1;
  toks[info.x * T_TOKENS + p0] = t;
  gates[info.x * T_TOKENS + p0] = __int_as_float(info.z);
  toks[info.y * T_TOKENS + p1] = t;
  gates[info.y * T_TOKENS + p1] = __int_as_float(info.w);
}

// ---------------- meta: 128-aligned block offsets per expert --------------
// meta[0..8] = block-offset prefix (blkoff), meta[16+e] = count[e]
__global__ void compute_meta(const int* __restrict__ counts, int* __restrict__ meta) {
  if (threadIdx.x == 0 && blockIdx.x == 0) {
    int off = 0;
    for (int e = 0; e < NEXP; e++) {
      meta[e] = off;
      int c = counts[e * 16];
      meta[16 + e] = c;
      off += (c + 127) >> 7;
    }
    meta[8] = off;
  }
}

// ---------------- W [K][N] fp32 -> Wt [N][K] bf16, per-z expert -----------
__global__ __launch_bounds__(256) void transpose_cvt64(
    const float* __restrict__ W, bf16* __restrict__ Wt, int K, int N) {
  W += (size_t)blockIdx.z * K * N;
  Wt += (size_t)blockIdx.z * K * N;
  __shared__ float tile[64][65];
  int bn = blockIdx.x * 64, bk = blockIdx.y * 64;
  int tx = threadIdx.x & 15, ty = threadIdx.x >> 4;
#pragma unroll
  for (int j = 0; j < 4; j++) {
    int k = bk + ty + j * 16;
    float4 v = *(const float4*)(W + (size_t)k * N + bn + tx * 4);
    tile[ty + j * 16][tx * 4 + 0] = v.x;
    tile[ty + j * 16][tx * 4 + 1] = v.y;
    tile[ty + j * 16][tx * 4 + 2] = v.z;
    tile[ty + j * 16][tx * 4 + 3] = v.w;
  }
  __syncthreads();
#pragma unroll
  for (int j = 0; j < 4; j++) {
    int n = bn + ty + j * 16;
    union { bf16 h[4]; uint2 u; } o;
    o.h[0] = __float2bfloat16(tile[tx * 4 + 0][ty + j * 16]);
    o.h[1] = __float2bfloat16(tile[tx * 4 + 1][ty + j * 16]);
    o.h[2] = __float2bfloat16(tile[tx * 4 + 2][ty + j * 16]);
    o.h[3] = __float2bfloat16(tile[tx * 4 + 3][ty + j * 16]);
    *(uint2*)(Wt + (size_t)n * K + bk + tx * 4) = o.u;
  }
}

// ================= FUSED PATH =================
// GEMM1 fused: H[slot] = gelu(X[tok] @ W1[e] + b1[e]); slot = blockIdx.y*128+row
__global__ __launch_bounds__(256) void moe_gemm1_f(
    const bf16* __restrict__ Xb, const bf16* __restrict__ Wt,
    const float* __restrict__ b1, bf16* __restrict__ H,
    const int* __restrict__ toks, const int* __restrict__ meta) {
  __shared__ __align__(16) bf16 As[128][32];
  __shared__ __align__(16) bf16 Bs[128][32];
  __shared__ int tids[128];
  __shared__ int smeta[24];
  int tid = threadIdx.x;
  if (tid < 24) smeta[tid] = meta[tid];
  __syncthreads();
  int y = blockIdx.y;
  if (y >= smeta[8]) return;
  int e = 0;
#pragma unroll
  for (int k = 1; k < NEXP; k++) if (y >= smeta[k]) e = k;
  int ne = smeta[16 + e];
  int row0 = (y - smeta[e]) * 128;
  int col0 = blockIdx.x * 128;
  const bf16* Wte = Wt + (size_t)e * MLP * DIM;
  const float* bias = b1 + e * MLP;
  const int* tokse = toks + e * T_TOKENS;

  if (tid < 128) {
    int r = row0 + tid;
    tids[tid] = tokse[r < ne ? r : ne - 1];
  }
  __syncthreads();

  int wave = tid >> 6, lane = tid & 63;
  int wr = (wave >> 1) * 64, wc = (wave & 1) * 64;
  int lr = lane & 15, quad = lane >> 4;
  int r0 = tid >> 2, seg = tid & 3;

  const bf16* pA0 = Xb + (size_t)tids[r0] * DIM + seg * 8;
  const bf16* pA1 = Xb + (size_t)tids[64 + r0] * DIM + seg * 8;
  const bf16* pB0 = Wte + (size_t)(col0 + r0) * DIM + seg * 8;
  const bf16* pB1 = Wte + (size_t)(col0 + 64 + r0) * DIM + seg * 8;
  char* lA = (char*)As + wave * 1024;
  char* lB = (char*)Bs + wave * 1024;

  float4v acc[4][4];
#pragma unroll
  for (int i = 0; i < 4; i++)
#pragma unroll
    for (int j = 0; j < 4; j++) acc[i][j] = (float4v)0.0f;

  for (int k0 = 0; k0 < DIM; k0 += 32) {
    gl2lds16(pA0 + k0, lA);
    gl2lds16(pA1 + k0, lA + 4096);
    gl2lds16(pB0 + k0, lB);
    gl2lds16(pB1 + k0, lB + 4096);
    __syncthreads();
    short8v a[4], b[4];
#pragma unroll
    for (int mt = 0; mt < 4; mt++)
      a[mt] = *(const short8v*)&As[wr + mt * 16 + lr][quad * 8];
#pragma unroll
    for (int nt = 0; nt < 4; nt++)
      b[nt] = *(const short8v*)&Bs[wc + nt * 16 + lr][quad * 8];
#pragma unroll
    for (int mt = 0; mt < 4; mt++)
#pragma unroll
      for (int nt = 0; nt < 4; nt++)
        acc[mt][nt] = __builtin_amdgcn_mfma_f32_16x16x32_bf16(a[mt], b[nt],
                                                              acc[mt][nt], 0, 0, 0);
    __syncthreads();
  }

#pragma unroll
  for (int mt = 0; mt < 4; mt++) {
#pragma unroll
    for (int r = 0; r < 4; r++) {
      int gr = wr + mt * 16 + quad * 4 + r;
      if (row0 + gr < ne) {
#pragma unroll
        for (int nt = 0; nt < 4; nt++) {
          int gc = col0 + wc + nt * 16 + lr;
          float v = acc[mt][nt][r] + bias[gc];
          v = 0.5f * v * (1.0f + erff(v * 0.70710678118f));
          H[(size_t)(y * 128 + gr) * MLP + gc] = __float2bfloat16(v);
        }
      }
    }
  }
}

// GEMM2 fused: out[tok] += g * (H[slot] @ W2[e] + b2[e])  (fp32 atomics)
__global__ __launch_bounds__(256) void moe_gemm2_f(
    const bf16* __restrict__ H, const bf16* __restrict__ Wt,
    const float* __restrict__ b2, float* __restrict__ out,
    const int* __restrict__ toks, const float* __restrict__ gates,
    const int* __restrict__ meta) {
  __shared__ __align__(16) bf16 As[128][32];
  __shared__ __align__(16) bf16 Bs[128][32];
  __shared__ int smeta[24];
  int tid = threadIdx.x;
  if (tid < 24) smeta[tid] = meta[tid];
  __syncthreads();
  int y = blockIdx.y;
  if (y >= smeta[8]) return;
  int e = 0;
#pragma unroll
  for (int k = 1; k < NEXP; k++) if (y >= smeta[k]) e = k;
  int ne = smeta[16 + e];
  int row0 = (y - smeta[e]) * 128;
  int col0 = blockIdx.x * 128;
  const bf16* Wte = Wt + (size_t)e * DIM * MLP;
  const float* bias = b2 + e * DIM;
  const int* tokse = toks + e * T_TOKENS;
  const float* gatese = gates + e * T_TOKENS;

  int wave = tid >> 6, lane = tid & 63;
  int wr = (wave >> 1) * 64, wc = (wave & 1) * 64;
  int lr = lane & 15, quad = lane >> 4;
  int r0 = tid >> 2, seg = tid & 3;

  const bf16* pA0 = H + (size_t)(y * 128 + r0) * MLP + seg * 8;
  const bf16* pA1 = H + (size_t)(y * 128 + 64 + r0) * MLP + seg * 8;
  const bf16* pB0 = Wte + (size_t)(col0 + r0) * MLP + seg * 8;
  const bf16* pB1 = Wte + (size_t)(col0 + 64 + r0) * MLP + seg * 8;
  char* lA = (char*)As + wave * 1024;
  char* lB = (char*)Bs + wave * 1024;

  float4v acc[4][4];
#pragma unroll
  for (int i = 0; i < 4; i++)
#pragma unroll
    for (int j = 0; j < 4; j++) acc[i][j] = (float4v)0.0f;

  for (int k0 = 0; k0 < MLP; k0 += 32) {
    gl2lds16(pA0 + k0, lA);
    gl2lds16(pA1 + k0, lA + 4096);
    gl2lds16(pB0 + k0, lB);
    gl2lds16(pB1 + k0, lB + 4096);
    __syncthreads();
    short8v a[4], b[4];
#pragma unroll
    for (int mt = 0; mt < 4; mt++)
      a[mt] = *(const short8v*)&As[wr + mt * 16 + lr][quad * 8];
#pragma unroll
    for (int nt = 0; nt < 4; nt++)
      b[nt] = *(const short8v*)&Bs[wc + nt * 16 + lr][quad * 8];
#pragma unroll
    for (int mt = 0; mt < 4; mt++)
#pragma unroll
      for (int nt = 0; nt < 4; nt++)
        acc[mt][nt] = __builtin_amdgcn_mfma_f32_16x16x32_bf16(a[mt], b[nt],
                                                              acc[mt][nt], 0, 0, 0);
    __syncthreads();
  }

#pragma unroll
  for (int mt = 0; mt < 4; mt++) {
#pragma unroll
    for (int r = 0; r < 4; r++) {
      int gr = wr + mt * 16 + quad * 4 + r;
      int grow = row0 + gr;
      if (grow < ne) {
        int t = tokse[grow];
        float g = gatese[grow];
#pragma unroll
        for (int nt = 0; nt < 4; nt++) {
          int gc = col0 + wc + nt * 16 + lr;
          atomicAdd(&out[(size_t)t * DIM + gc], g * (acc[mt][nt][r] + bias[gc]));
        }
      }
    }
  }
}

// ================= SEQUENTIAL FALLBACK (round-2, proven) =================
__global__ __launch_bounds__(256) void moe_gemm1_s(
    const bf16* __restrict__ Xb, const bf16* __restrict__ Wt,
    const float* __restrict__ bias, bf16* __restrict__ H,
    const int* __restrict__ toks, const int* __restrict__ cntp) {
  int ne = *cntp;
  int row0 = blockIdx.y * 128;
  if (row0 >= ne) return;
  int col0 = blockIdx.x * 128;
  __shared__ __align__(16) bf16 As[128][32];
  __shared__ __align__(16) bf16 Bs[128][32];
  __shared__ int tids[128];
  int tid = threadIdx.x;
  if (tid < 128) {
    int r = row0 + tid;
    tids[tid] = toks[r < ne ? r : ne - 1];
  }
  __syncthreads();
  int wave = tid >> 6, lane = tid & 63;
  int wr = (wave >> 1) * 64, wc = (wave & 1) * 64;
  int lr = lane & 15, quad = lane >> 4;
  int r0 = tid >> 2, seg = tid & 3;
  const bf16* pA0 = Xb + (size_t)tids[r0] * DIM + seg * 8;
  const bf16* pA1 = Xb + (size_t)tids[64 + r0] * DIM + seg * 8;
  const bf16* pB0 = Wt + (size_t)(col0 + r0) * DIM + seg * 8;
  const bf16* pB1 = Wt + (size_t)(col0 + 64 + r0) * DIM + seg * 8;
  char* lA = (char*)As + wave * 1024;
  char* lB = (char*)Bs + wave * 1024;
  float4v acc[4][4];
#pragma unroll
  for (int i = 0; i < 4; i++)
#pragma unroll
    for (int j = 0; j < 4; j++) acc[i][j] = (float4v)0.0f;
  for (int k0 = 0; k0 < DIM; k0 += 32) {
    gl2lds16(pA0 + k0, lA);
    gl2lds16(pA1 + k0, lA + 4096);
    gl2lds16(pB0 + k0, lB);
    gl2lds16(pB1 + k0, lB + 4096);
    __syncthreads();
    short8v a[4], b[4];
#pragma unroll
    for (int mt = 0; mt < 4; mt++)
      a[mt] = *(const short8v*)&As[wr + mt * 16 + lr][quad * 8];
#pragma unroll
    for (int nt = 0; nt < 4; nt++)
      b[nt] = *(const short8v*)&Bs[wc + nt * 16 + lr][quad * 8];
#pragma unroll
    for (int mt = 0; mt < 4; mt++)
#pragma unroll
      for (int nt = 0; nt < 4; nt++)
        acc[mt][nt] = __builtin_amdgcn_mfma_f32_16x16x32_bf16(a[mt], b[nt],
                                                              acc[mt][nt], 0, 0, 0);
    __syncthreads();
  }
#pragma unroll
  for (int mt = 0; mt < 4; mt++) {
#pragma unroll
    for (int r = 0; r < 4; r++) {
      int gr = wr + mt * 16 + quad * 4 + r;
      if (row0 + gr < ne) {
#pragma unroll
        for (int nt = 0; nt < 4; nt++) {
          int gc = col0 + wc + nt * 16 + lr;
          float v = acc[mt][nt][r] + bias[gc];
          v = 0.5f * v * (1.0f + erff(v * 0.70710678118f));
          H[(size_t)(row0 + gr) * MLP + gc] = __float2bfloat16(v);
        }
      }
    }
  }
}

__global__ __launch_bounds__(256) void moe_gemm2_s(
    const bf16* __restrict__ H, const bf16* __restrict__ Wt,
    const float* __restrict__ bias, float* __restrict__ out,
    const int* __restrict__ toks, const float* __restrict__ gates,
    const int* __restrict__ cntp) {
  int ne = *cntp;
  int row0 = blockIdx.y * 128;
  if (row0 >= ne) return;
  int col0 = blockIdx.x * 64;
  __shared__ __align__(16) bf16 As[128][32];
  __shared__ __align__(16) bf16 Bs[64][32];
  int tid = threadIdx.x;
  int wave = tid >> 6, lane = tid & 63;
  int wr = wave * 32;
  int lr = lane & 15, quad = lane >> 4;
  int r0 = tid >> 2, seg = tid & 3;
  const bf16* pA0 = H + (size_t)(row0 + r0) * MLP + seg * 8;
  const bf16* pA1 = H + (size_t)(row0 + 64 + r0) * MLP + seg * 8;
  const bf16* pB0 = Wt + (size_t)(col0 + r0) * MLP + seg * 8;
  char* lA = (char*)As + wave * 1024;
  char* lB = (char*)Bs + wave * 1024;
  float4v acc[2][4];
#pragma unroll
  for (int i = 0; i < 2; i++)
#pragma unroll
    for (int j = 0; j < 4; j++) acc[i][j] = (float4v)0.0f;
  for (int k0 = 0; k0 < MLP; k0 += 32) {
    gl2lds16(pA0 + k0, lA);
    gl2lds16(pA1 + k0, lA + 4096);
    gl2lds16(pB0 + k0, lB);
    __syncthreads();
    short8v a[2], b[4];
#pragma unroll
    for (int mt = 0; mt < 2; mt++)
      a[mt] = *(const short8v*)&As[wr + mt * 16 + lr][quad * 8];
#pragma unroll
    for (int nt = 0; nt < 4; nt++)
      b[nt] = *(const short8v*)&Bs[nt * 16 + lr][quad * 8];
#pragma unroll
    for (int mt = 0; mt < 2; mt++)
#pragma unroll
      for (int nt = 0; nt < 4; nt++)
        acc[mt][nt] = __builtin_amdgcn_mfma_f32_16x16x32_bf16(a[mt], b[nt],
                                                              acc[mt][nt], 0, 0, 0);
    __syncthreads();
  }
#pragma unroll
  for (int mt = 0; mt < 2; mt++) {
#pragma unroll
    for (int r = 0; r < 4; r++) {
      int gr = wr + mt * 16 + quad * 4 + r;
      int grow = row0 + gr;
      if (grow < ne) {
        int t = toks[grow];
        float g = gates[grow];
#pragma unroll
        for (int nt = 0; nt < 4; nt++) {
          int gc = col0 + nt * 16 + lr;
          out[(size_t)t * DIM + gc] += g * (acc[mt][nt][r] + bias[gc]);
        }
      }
    }
  }
}

extern "C" void kernel_launch(void* const* d_in, const int* in_sizes, int n_in,
                              void* d_out, int out_size, void* d_ws, size_t ws_size,
                              hipStream_t stream) {
  const float* x  = (const float*)d_in[0];
  const float* rw = (const float*)d_in[1];
  const float* rb = (const float*)d_in[2];
  const float* eb = (const float*)d_in[3];
  const float* w1 = (const float*)d_in[4];
  const float* b1 = (const float*)d_in[5];
  const float* w2 = (const float*)d_in[6];
  const float* b2 = (const float*)d_in[7];
  float* out = (float*)d_out;
  char* ws = (char*)d_ws;

  // Fused layout: [H 142.6MB][xb 16MB][W 64MB (w1t then w2t)][aux]
  const size_t sz_H  = (size_t)MAXSLOT * MLP * 2;        // 142,606,336
  const size_t sz_xb = (size_t)T_TOKENS * DIM * 2;       // 16,777,216
  const size_t sz_W  = (size_t)NEXP * DIM * MLP * 2;     // 67,108,864
  const size_t off_xb = sz_H, off_W = off_xb + sz_xb, off_aux = off_W + sz_W;
  const size_t aux_need = 131072 + 512 + 128 + 262144 + 262144;
  const size_t need = off_aux + aux_need;

  if (ws_size >= need) {
    bf16* Hbuf = (bf16*)ws;
    bf16* xb   = (bf16*)(ws + off_xb);
    bf16* wT   = (bf16*)(ws + off_W);   // holds w1t during gemm1, w2t after
    char* aux  = ws + off_aux;
    int4*  tokinfo = (int4*)aux;
    int*   counts  = (int*)(aux + 131072);
    int*   meta    = (int*)(aux + 131072 + 512);
    int*   toks    = (int*)(aux + 131072 + 512 + 128);
    float* gates   = (float*)(aux + 131072 + 512 + 128 + 262144);

    hipMemsetAsync(counts, 0, 512, stream);
    hipMemsetAsync(d_out, 0, (size_t)T_TOKENS * DIM * sizeof(float), stream);

    router_convert<<<T_TOKENS / 16, 256, 0, stream>>>(x, rw, rb, eb, xb, tokinfo);
    build_lists<<<T_TOKENS / 256, 256, 0, stream>>>(tokinfo, counts, toks, gates);
    compute_meta<<<1, 64, 0, stream>>>(counts, meta);

    transpose_cvt64<<<dim3(MLP / 64, DIM / 64, NEXP), 256, 0, stream>>>(
        w1, wT, DIM, MLP);
    moe_gemm1_f<<<dim3(MLP / 128, MAXYB), 256, 0, stream>>>(
        xb, wT, b1, Hbuf, toks, meta);
    transpose_cvt64<<<dim3(DIM / 64, MLP / 64, NEXP), 256, 0, stream>>>(
        w2, wT, MLP, DIM);
    moe_gemm2_f<<<dim3(DIM / 128, MAXYB), 256, 0, stream>>>(
        Hbuf, wT, b2, out, toks, gates, meta);
  } else {
    // Round-2 sequential fallback (~97 MB ws)
    bf16* xb   = (bf16*)ws;
    bf16* w1t  = (bf16*)(ws + (size_t)(16 << 20));
    bf16* w2t  = (bf16*)(ws + (size_t)(24 << 20));
    bf16* Hbuf = (bf16*)(ws + (size_t)(32 << 20));
    char* aux  = ws + (size_t)(96 << 20);
    int4*  tokinfo = (int4*)aux;
    int*   counts  = (int*)(aux + 131072);
    int*   toks    = (int*)(aux + 131072 + 512);
    float* gates   = (float*)(aux + 131072 + 512 + 262144);

    hipMemsetAsync(counts, 0, 512, stream);
    hipMemsetAsync(d_out, 0, (size_t)T_TOKENS * DIM * sizeof(float), stream);

    router_convert<<<T_TOKENS / 16, 256, 0, stream>>>(x, rw, rb, eb, xb, tokinfo);
    build_lists<<<T_TOKENS / 256, 256, 0, stream>>>(tokinfo, counts, toks, gates);

    for (int e = 0; e < NEXP; e++) {
      transpose_cvt64<<<dim3(MLP / 64, DIM / 64, 1), 256, 0, stream>>>(
          w1 + (size_t)e * DIM * MLP, w1t, DIM, MLP);
      moe_gemm1_s<<<dim3(MLP / 128, T_TOKENS / 128), 256, 0, stream>>>(
          xb, w1t, b1 + (size_t)e * MLP, Hbuf, toks + e * T_TOKENS,
          counts + e * 16);
      transpose_cvt64<<<dim3(DIM / 64, MLP / 64, 1), 256, 0, stream>>>(
          w2 + (size_t)e * MLP * DIM, w2t, MLP, DIM);
      moe_gemm2_s<<<dim3(DIM / 64, T_TOKENS / 128), 256, 0, stream>>>(
          Hbuf, w2t, b2 + (size_t)e * DIM, out, toks + e * T_TOKENS,
          gates + e * T_TOKENS, counts + e * 16);
    }
  }
}